// Round 2
// baseline (3234.996 us; speedup 1.0000x reference)
//
#include <hip/hip_runtime.h>

// CompressiveMemory — fp32 baseline pipeline, scratch in __device__ globals.
//
// Key insight: the reference's "buggy view" reshape means each (b,seg,h)
// (512x64) q/k/v tile is a CONTIGUOUS 32x1024 row-block of the projection at
// row offset b*8192 + seg*512 + h*32, reinterpreted row-major:
//   q[b,seg,h,s,d] = proj[b, seg*512 + h*32 + (s>>4), (s&15)*64 + d].
// The output reshape is its exact inverse, so att tiles write back
// contiguously and the final GEMM runs on the plain (16384,1024) layout.
// z is rank-degenerate (denominator = rowsum_sq[s] * Z[v], Z = inclusive
// prefix of sk column sums); mem is an exclusive prefix of M_seg = sk^T v.
//
// Round-1 change: round 0 carved 285 MB from d_ws (size unknown) -> GPU
// memory fault / abort. Scratch now lives in __device__ globals allocated at
// module load; d_ws is unused. Prefix scan is done in place.

#define H_ 16
#define DK_ 64
#define DV_ 64
#define SEG_ 512
#define NSEG_ 16
#define B_ 2
#define T_ 8192
#define D_ 1024
#define BT_ 16384

#define NPROJ ((size_t)BT_ * D_)   // 16,777,216 floats = 64 MB

__device__ float g_q[NPROJ];
__device__ float g_k[NPROJ];
__device__ float g_v[NPROJ];
__device__ float g_att[NPROJ];
__device__ float g_M[(size_t)512 * 4096];  // Mseg -> exclusive-prefix mem (in place)
__device__ float g_z[(size_t)512 * 64];    // zsum -> inclusive-prefix Z  (in place)

__device__ __forceinline__ float elu1(float x) {
    // elu(x)+1 = x+1 (x>0) else exp(x)
    return x > 0.f ? x + 1.f : __expf(x);
}

// C[m,n] = sum_k A[m,k] * W[n,k]   (A: MxK row-major, W: NxK row-major)
__global__ __launch_bounds__(256) void gemm_nt_128(
    const float* __restrict__ A, const float* __restrict__ W,
    float* __restrict__ C, int M, int N, int K)
{
    __shared__ float As[8][128];
    __shared__ float Bs[8][128];
    const int t  = threadIdx.x;
    const int bm = blockIdx.y * 128;
    const int bn = blockIdx.x * 128;
    const int tx = t & 15, ty = t >> 4;
    const int lr = t >> 1;
    const int lc = (t & 1) * 4;
    const float* Ap = A + (size_t)(bm + lr) * K + lc;
    const float* Wp = W + (size_t)(bn + lr) * K + lc;
    float acc[8][8];
#pragma unroll
    for (int i = 0; i < 8; ++i)
#pragma unroll
        for (int j = 0; j < 8; ++j) acc[i][j] = 0.f;

    for (int k0 = 0; k0 < K; k0 += 8) {
        float4 a4 = *(const float4*)(Ap + k0);
        float4 w4 = *(const float4*)(Wp + k0);
        __syncthreads();
        As[lc + 0][lr] = a4.x; As[lc + 1][lr] = a4.y;
        As[lc + 2][lr] = a4.z; As[lc + 3][lr] = a4.w;
        Bs[lc + 0][lr] = w4.x; Bs[lc + 1][lr] = w4.y;
        Bs[lc + 2][lr] = w4.z; Bs[lc + 3][lr] = w4.w;
        __syncthreads();
#pragma unroll
        for (int kk = 0; kk < 8; ++kk) {
            float a[8], b[8];
#pragma unroll
            for (int i = 0; i < 8; ++i) a[i] = As[kk][ty * 8 + i];
#pragma unroll
            for (int j = 0; j < 8; ++j) b[j] = Bs[kk][tx * 8 + j];
#pragma unroll
            for (int i = 0; i < 8; ++i)
#pragma unroll
                for (int j = 0; j < 8; ++j) acc[i][j] += a[i] * b[j];
        }
    }
#pragma unroll
    for (int i = 0; i < 8; ++i) {
        float* cp = C + (size_t)(bm + ty * 8 + i) * N + bn + tx * 8;
        *(float4*)cp       = make_float4(acc[i][0], acc[i][1], acc[i][2], acc[i][3]);
        *(float4*)(cp + 4) = make_float4(acc[i][4], acc[i][5], acc[i][6], acc[i][7]);
    }
}

// Per (b,h,seg): M_seg[d][v] = sum_i sk[i,d]*v[i,v]; zsum[d] = sum_i sk[i,d]
__global__ __launch_bounds__(256) void seg_stats(
    const float* __restrict__ kproj, const float* __restrict__ vproj,
    float* __restrict__ Mseg, float* __restrict__ zsum)
{
    __shared__ float ks[64][68];
    __shared__ float vs[64][68];
    const int idx = blockIdx.x;          // (b*H+h)*16 + seg
    const int seg = idx & 15;
    const int bh  = idx >> 4;
    const int h   = bh & 15;
    const int b   = bh >> 4;
    const size_t base = ((size_t)b * T_ + (size_t)seg * SEG_ + (size_t)h * 32) * D_;
    const float* kt = kproj + base;      // (512,64) contiguous tile
    const float* vt = vproj + base;
    const int t  = threadIdx.x;
    const int d0 = (t >> 4) * 4;
    const int v0 = (t & 15) * 4;
    const int lr = t >> 2;
    const int lc = (t & 3) * 16;
    float acc[4][4];
#pragma unroll
    for (int i = 0; i < 4; ++i)
#pragma unroll
        for (int j = 0; j < 4; ++j) acc[i][j] = 0.f;
    float zacc = 0.f;

    for (int c0 = 0; c0 < SEG_; c0 += 64) {
        __syncthreads();
#pragma unroll
        for (int u = 0; u < 4; ++u) {
            float4 kv = *(const float4*)(kt + (size_t)(c0 + lr) * 64 + lc + u * 4);
            float4 vv = *(const float4*)(vt + (size_t)(c0 + lr) * 64 + lc + u * 4);
            ks[lr][lc + u * 4 + 0] = elu1(kv.x);
            ks[lr][lc + u * 4 + 1] = elu1(kv.y);
            ks[lr][lc + u * 4 + 2] = elu1(kv.z);
            ks[lr][lc + u * 4 + 3] = elu1(kv.w);
            vs[lr][lc + u * 4 + 0] = vv.x;
            vs[lr][lc + u * 4 + 1] = vv.y;
            vs[lr][lc + u * 4 + 2] = vv.z;
            vs[lr][lc + u * 4 + 3] = vv.w;
        }
        __syncthreads();
#pragma unroll 8
        for (int i = 0; i < 64; ++i) {
            float a0 = ks[i][d0 + 0], a1 = ks[i][d0 + 1];
            float a2 = ks[i][d0 + 2], a3 = ks[i][d0 + 3];
            float b0 = vs[i][v0 + 0], b1 = vs[i][v0 + 1];
            float b2 = vs[i][v0 + 2], b3 = vs[i][v0 + 3];
            acc[0][0] += a0 * b0; acc[0][1] += a0 * b1; acc[0][2] += a0 * b2; acc[0][3] += a0 * b3;
            acc[1][0] += a1 * b0; acc[1][1] += a1 * b1; acc[1][2] += a1 * b2; acc[1][3] += a1 * b3;
            acc[2][0] += a2 * b0; acc[2][1] += a2 * b1; acc[2][2] += a2 * b2; acc[2][3] += a2 * b3;
            acc[3][0] += a3 * b0; acc[3][1] += a3 * b1; acc[3][2] += a3 * b2; acc[3][3] += a3 * b3;
        }
        if (t < 64) {
#pragma unroll 8
            for (int i = 0; i < 64; ++i) zacc += ks[i][t];
        }
    }
    float* Mout = Mseg + (size_t)idx * 4096;
#pragma unroll
    for (int i = 0; i < 4; ++i)
        *(float4*)(Mout + (size_t)(d0 + i) * 64 + v0) =
            make_float4(acc[i][0], acc[i][1], acc[i][2], acc[i][3]);
    if (t < 64) zsum[(size_t)idx * 64 + t] = zacc;
}

// Per (b,h): IN-PLACE exclusive prefix of M (per-seg 64x64 tiles) and
// in-place inclusive prefix of z (per-seg 64 col-sums).
__global__ __launch_bounds__(256) void prefix_scan(
    float* __restrict__ M, float* __restrict__ z)
{
    const int bh = blockIdx.x;   // 0..31
    const int t  = threadIdx.x;
    float run[16];
#pragma unroll
    for (int u = 0; u < 16; ++u) run[u] = 0.f;
    float runz = 0.f;
    for (int seg = 0; seg < NSEG_; ++seg) {
        const size_t o = ((size_t)bh * NSEG_ + seg) * 4096 + (size_t)t * 16;
#pragma unroll
        for (int u = 0; u < 16; u += 4) {
            float4 m = *(const float4*)(M + o + u);
            *(float4*)(M + o + u) = make_float4(run[u], run[u+1], run[u+2], run[u+3]);
            run[u] += m.x; run[u+1] += m.y; run[u+2] += m.z; run[u+3] += m.w;
        }
        if (t < 64) {
            const size_t oz = ((size_t)bh * NSEG_ + seg) * 64 + t;
            runz += z[oz];
            z[oz] = runz;   // inclusive
        }
    }
}

// Per (b,h,seg,qchunk of 64 rows): flash softmax attention + memory read + gate
__global__ __launch_bounds__(256) void attn_kernel(
    const float* __restrict__ qproj, const float* __restrict__ kproj,
    const float* __restrict__ vproj, const float* __restrict__ memb,
    const float* __restrict__ Zaf, const float* __restrict__ betas,
    float* __restrict__ attout)
{
    __shared__ float qs[64][68];
    __shared__ float ks[64][68];   // mem tile, then k chunks, then reused for P
    __shared__ float vs[64][68];
    __shared__ float Zsh[64];
    __shared__ float gsh[64];
    const int idx  = blockIdx.x;          // (bh*16+seg)*8 + qc
    const int qc   = idx & 7;
    const int rest = idx >> 3;            // bh*16+seg
    const int seg  = rest & 15;
    const int bh   = rest >> 4;
    const int h    = bh & 15;
    const int b    = bh >> 4;
    const size_t base = ((size_t)b * T_ + (size_t)seg * SEG_ + (size_t)h * 32) * D_;
    const float* qt = qproj + base + (size_t)qc * 64 * 64;
    const float* kt = kproj + base;
    const float* vt = vproj + base;
    const float* mb = memb + (size_t)rest * 4096;
    const float* Zp = Zaf + (size_t)rest * 64;
    const int t  = threadIdx.x;
    const int r  = t >> 2;    // q-row 0..63
    const int p  = t & 3;     // quarter: owns score cols / v dims [p*16, p*16+16)
    const int lr = t >> 2;
    const int lc = (t & 3) * 16;

    // stage q chunk and mem tile (mem temporarily in ks)
#pragma unroll
    for (int u = 0; u < 4; ++u) {
        *(float4*)&qs[lr][lc + u * 4] = *(const float4*)(qt + (size_t)lr * 64 + lc + u * 4);
        *(float4*)&ks[lr][lc + u * 4] = *(const float4*)(mb + (size_t)lr * 64 + lc + u * 4);
    }
    if (t < 64) {
        Zsh[t] = Zp[t];
        gsh[t] = 1.f / (1.f + __expf(-betas[h * 64 + t]));
    }
    __syncthreads();

    // att_mem numerator over this thread's v window + rowsum of sq
    float num[16];
#pragma unroll
    for (int u = 0; u < 16; ++u) num[u] = 0.f;
    float rowsum = 0.f;
#pragma unroll 4
    for (int d = 0; d < 64; ++d) {
        float sq = elu1(qs[r][d]);
        rowsum += sq;
#pragma unroll
        for (int u = 0; u < 4; ++u) {
            float4 mm = *(const float4*)&ks[d][p * 16 + u * 4];
            num[u*4+0] += sq * mm.x;
            num[u*4+1] += sq * mm.y;
            num[u*4+2] += sq * mm.z;
            num[u*4+3] += sq * mm.w;
        }
    }

    float o16[16];
#pragma unroll
    for (int u = 0; u < 16; ++u) o16[u] = 0.f;
    float m_r = -1e30f, l_r = 0.f;

    for (int kb = 0; kb < 8; ++kb) {
        __syncthreads();
#pragma unroll
        for (int u = 0; u < 4; ++u) {
            *(float4*)&ks[lr][lc + u * 4] =
                *(const float4*)(kt + (size_t)(kb * 64 + lr) * 64 + lc + u * 4);
            *(float4*)&vs[lr][lc + u * 4] =
                *(const float4*)(vt + (size_t)(kb * 64 + lr) * 64 + lc + u * 4);
        }
        __syncthreads();

        // scores for this thread's 16 k-columns
        float s[16];
#pragma unroll
        for (int j = 0; j < 16; ++j) s[j] = 0.f;
#pragma unroll 4
        for (int d4 = 0; d4 < 16; ++d4) {
            float4 q4 = *(const float4*)&qs[r][d4 * 4];
#pragma unroll
            for (int j = 0; j < 16; ++j) {
                float4 k4 = *(const float4*)&ks[p * 16 + j][d4 * 4];
                s[j] += q4.x * k4.x + q4.y * k4.y + q4.z * k4.z + q4.w * k4.w;
            }
        }
        float mx = -1e30f;
#pragma unroll
        for (int j = 0; j < 16; ++j) { s[j] *= 0.125f; mx = fmaxf(mx, s[j]); }
        mx = fmaxf(mx, __shfl_xor(mx, 1, 4));
        mx = fmaxf(mx, __shfl_xor(mx, 2, 4));
        const float mnew = fmaxf(m_r, mx);
        const float corr = __expf(m_r - mnew);
        float pv[16];
        float psum = 0.f;
#pragma unroll
        for (int j = 0; j < 16; ++j) { pv[j] = __expf(s[j] - mnew); psum += pv[j]; }
        psum += __shfl_xor(psum, 1, 4);
        psum += __shfl_xor(psum, 2, 4);
        l_r = l_r * corr + psum;
        m_r = mnew;
#pragma unroll
        for (int u = 0; u < 16; ++u) o16[u] *= corr;

        // publish P into ks (done reading k by now), then accumulate P @ v
        __syncthreads();
#pragma unroll
        for (int u = 0; u < 4; ++u)
            *(float4*)&ks[r][p * 16 + u * 4] =
                make_float4(pv[u*4+0], pv[u*4+1], pv[u*4+2], pv[u*4+3]);
        __syncthreads();
#pragma unroll 4
        for (int i4 = 0; i4 < 16; ++i4) {
            float4 pq = *(const float4*)&ks[r][i4 * 4];
            float pw[4] = {pq.x, pq.y, pq.z, pq.w};
#pragma unroll
            for (int c = 0; c < 4; ++c) {
                const int i = i4 * 4 + c;
                const float w = pw[c];
#pragma unroll
                for (int u = 0; u < 4; ++u) {
                    float4 vv = *(const float4*)&vs[i][p * 16 + u * 4];
                    o16[u*4+0] += w * vv.x;
                    o16[u*4+1] += w * vv.y;
                    o16[u*4+2] += w * vv.z;
                    o16[u*4+3] += w * vv.w;
                }
            }
        }
    }

    const float inv_l  = 1.f / l_r;
    const float inv_rs = 1.f / rowsum;
    float* op = attout + base + (size_t)(qc * 64 + r) * 64 + p * 16;
#pragma unroll
    for (int u = 0; u < 4; ++u) {
        float res[4];
#pragma unroll
        for (int c = 0; c < 4; ++c) {
            const int vv = p * 16 + u * 4 + c;
            const float adot = o16[u*4+c] * inv_l;
            const float amem = num[u*4+c] * inv_rs / Zsh[vv];
            const float g = gsh[vv];
            res[c] = g * amem + (1.f - g) * adot;
        }
        *(float4*)(op + u * 4) = make_float4(res[0], res[1], res[2], res[3]);
    }
}

extern "C" void kernel_launch(void* const* d_in, const int* in_sizes, int n_in,
                              void* d_out, int out_size, void* d_ws, size_t ws_size,
                              hipStream_t stream) {
    const float* x     = (const float*)d_in[0];
    const float* Wq    = (const float*)d_in[1];
    const float* Wk    = (const float*)d_in[2];
    const float* Wv    = (const float*)d_in[3];
    const float* Wout  = (const float*)d_in[4];
    const float* betas = (const float*)d_in[5];
    float* out = (float*)d_out;
    (void)d_ws; (void)ws_size;

    float *q, *k, *v, *att, *M, *z;
    hipGetSymbolAddress((void**)&q,   HIP_SYMBOL(g_q));
    hipGetSymbolAddress((void**)&k,   HIP_SYMBOL(g_k));
    hipGetSymbolAddress((void**)&v,   HIP_SYMBOL(g_v));
    hipGetSymbolAddress((void**)&att, HIP_SYMBOL(g_att));
    hipGetSymbolAddress((void**)&M,   HIP_SYMBOL(g_M));
    hipGetSymbolAddress((void**)&z,   HIP_SYMBOL(g_z));

    dim3 gg(D_ / 128, BT_ / 128);                    // (8, 128)
    gemm_nt_128<<<gg, 256, 0, stream>>>(x, Wq, q, BT_, D_, D_);
    gemm_nt_128<<<gg, 256, 0, stream>>>(x, Wk, k, BT_, D_, D_);
    gemm_nt_128<<<gg, 256, 0, stream>>>(x, Wv, v, BT_, D_, D_);
    seg_stats<<<B_ * H_ * NSEG_, 256, 0, stream>>>(k, v, M, z);
    prefix_scan<<<B_ * H_, 256, 0, stream>>>(M, z);
    attn_kernel<<<B_ * H_ * NSEG_ * 8, 256, 0, stream>>>(q, k, v, M, z, betas, att);
    gemm_nt_128<<<gg, 256, 0, stream>>>(att, Wout, out, BT_, D_, D_);
}

// Round 3
// 1676.590 us; speedup vs baseline: 1.9295x; 1.9295x over previous
//
#include <hip/hip_runtime.h>

// CompressiveMemory — round 3.
//  * GEMMs: split-bf16 (A=Ah+Al, B=Bh+Bl, C≈AhBh+AlBh+AhBl) on 16x16x32 bf16
//    MFMA, m97-style 128x128 tile with global_load_lds width=16. ~fp32 accuracy
//    (residual ~2^-16) on the 2.5PF matrix pipe instead of 157TF fp32 VALU.
//  * attn: score-loop column ownership interleaved (col=4j+p, was p*16+j).
//    Old layout: 4 p-rows 4352B apart = same bank quad -> 4-way conflict on
//    every ds_read_b128 (SQ_LDS_BANK_CONFLICT 4.16e8 ~= 45% of attn runtime).
//    New layout: rows 4j+p land on quads {0,4,8,12} -> conflict-free.
//  * attn epilogue writes att as bf16 hi/lo directly (feeds the out-GEMM).
//
// View insight (unchanged): each (b,seg,h) (512x64) tile is the CONTIGUOUS
// 32x1024 row-block of the projection at row b*8192+seg*512+h*32; output
// reshape is its exact inverse. z is rank-degenerate; mem is an exclusive
// prefix of M_seg = sk^T v.

#define H_ 16
#define SEG_ 512
#define NSEG_ 16
#define B_ 2
#define T_ 8192
#define D_ 1024
#define BT_ 16384

#define NPROJ ((size_t)BT_ * D_)   // 16,777,216
#define NW ((size_t)D_ * D_)       // 1,048,576

__device__ float g_q[NPROJ];
__device__ float g_k[NPROJ];
__device__ float g_v[NPROJ];
__device__ unsigned short g_xh[NPROJ], g_xl[NPROJ];
__device__ unsigned short g_ath[NPROJ], g_atl[NPROJ];
__device__ unsigned short g_wqh[NW], g_wql[NW];
__device__ unsigned short g_wkh[NW], g_wkl[NW];
__device__ unsigned short g_wvh[NW], g_wvl[NW];
__device__ unsigned short g_woh[NW], g_wol[NW];
__device__ float g_M[(size_t)512 * 4096];
__device__ float g_z[(size_t)512 * 64];

typedef __attribute__((ext_vector_type(8))) short short8;
typedef __attribute__((ext_vector_type(4))) float f32x4;

__device__ __forceinline__ float elu1(float x) {
    return x > 0.f ? x + 1.f : __expf(x);
}
__device__ __forceinline__ unsigned short f2bf(float x) {
    unsigned u = __float_as_uint(x);
    u += 0x7fffu + ((u >> 16) & 1u);           // RNE
    return (unsigned short)(u >> 16);
}
__device__ __forceinline__ float bf2f(unsigned short h) {
    return __uint_as_float((unsigned)h << 16);
}
__device__ __forceinline__ void load_lds16(const unsigned short* g, unsigned short* l) {
    __builtin_amdgcn_global_load_lds(
        (const __attribute__((address_space(1))) unsigned int*)g,
        (__attribute__((address_space(3))) unsigned int*)l, 16, 0, 0);
}

// fp32 -> (bf16 hi, bf16 lo). 4 elems/thread.
__global__ __launch_bounds__(256) void split_bf16(
    const float* __restrict__ in, unsigned short* __restrict__ hi,
    unsigned short* __restrict__ lo, int n)
{
    int i = (blockIdx.x * 256 + threadIdx.x) * 4;
    if (i >= n) return;
    float4 x = *(const float4*)(in + i);
    ushort4 h, l;
    h.x = f2bf(x.x); l.x = f2bf(x.x - bf2f(h.x));
    h.y = f2bf(x.y); l.y = f2bf(x.y - bf2f(h.y));
    h.z = f2bf(x.z); l.z = f2bf(x.z - bf2f(h.z));
    h.w = f2bf(x.w); l.w = f2bf(x.w - bf2f(h.w));
    *(ushort4*)(hi + i) = h;
    *(ushort4*)(lo + i) = l;
}

// C[m,n] = sum_k A[m,k]*B[n,k], A,B given as bf16 hi/lo pairs; C fp32.
// 128x128 tile, BK=32, 256 thr = 4 waves (2x2), wave tile 64x64 (4x4 frags).
#define BK 32
__global__ __launch_bounds__(256) void gemm_bt_split(
    const unsigned short* __restrict__ Ah, const unsigned short* __restrict__ Al,
    const unsigned short* __restrict__ Bh, const unsigned short* __restrict__ Bl,
    float* __restrict__ C, int M, int N, int K)
{
    __shared__ unsigned short sAh[128 * BK], sAl[128 * BK];
    __shared__ unsigned short sBh[128 * BK], sBl[128 * BK];
    const int t = threadIdx.x;
    const int lane = t & 63, wave = t >> 6;
    const int m0 = blockIdx.y * 128, n0 = blockIdx.x * 128;
    const int wm = (wave & 1) * 64, wn = (wave >> 1) * 64;
    // staging: wave stages rows [wave*32, wave*32+32); lane -> row wave*32+i*16+(lane>>2),
    // byte-col (lane&3)*16. LDS [128][32] bf16 row-major matches lane*16B exactly.
    const int srow = wave * 32 + (lane >> 2);
    const int scol = (lane & 3) * 8;
    const int fr = lane & 15, fq = (lane >> 4) * 8;

    f32x4 acc[4][4];
#pragma unroll
    for (int i = 0; i < 4; ++i)
#pragma unroll
        for (int j = 0; j < 4; ++j) acc[i][j] = (f32x4)0.f;

    for (int k0 = 0; k0 < K; k0 += BK) {
        __syncthreads();
#pragma unroll
        for (int i = 0; i < 2; ++i) {
            const size_t ga = (size_t)(m0 + srow + i * 16) * K + k0 + scol;
            const size_t gb = (size_t)(n0 + srow + i * 16) * K + k0 + scol;
            const int lb = (wave * 32 + i * 16) * BK;   // wave-uniform LDS base
            load_lds16(Ah + ga, &sAh[lb]);
            load_lds16(Al + ga, &sAl[lb]);
            load_lds16(Bh + gb, &sBh[lb]);
            load_lds16(Bl + gb, &sBl[lb]);
        }
        __syncthreads();
        short8 ah[4], al[4], bh[4], bl[4];
#pragma unroll
        for (int i = 0; i < 4; ++i) {
            ah[i] = *(const short8*)&sAh[(wm + i * 16 + fr) * BK + fq];
            al[i] = *(const short8*)&sAl[(wm + i * 16 + fr) * BK + fq];
            bh[i] = *(const short8*)&sBh[(wn + i * 16 + fr) * BK + fq];
            bl[i] = *(const short8*)&sBl[(wn + i * 16 + fr) * BK + fq];
        }
#pragma unroll
        for (int i = 0; i < 4; ++i)
#pragma unroll
            for (int j = 0; j < 4; ++j) {
                acc[i][j] = __builtin_amdgcn_mfma_f32_16x16x32_bf16(ah[i], bh[j], acc[i][j], 0, 0, 0);
                acc[i][j] = __builtin_amdgcn_mfma_f32_16x16x32_bf16(al[i], bh[j], acc[i][j], 0, 0, 0);
                acc[i][j] = __builtin_amdgcn_mfma_f32_16x16x32_bf16(ah[i], bl[j], acc[i][j], 0, 0, 0);
            }
    }
    // C/D layout: col=lane&15, row=(lane>>4)*4+reg  [m89]
    const int ccol = lane & 15, crow = (lane >> 4) * 4;
#pragma unroll
    for (int i = 0; i < 4; ++i)
#pragma unroll
        for (int j = 0; j < 4; ++j) {
            float* cp = C + (size_t)(m0 + wm + i * 16 + crow) * N + (n0 + wn + j * 16 + ccol);
#pragma unroll
            for (int r = 0; r < 4; ++r) cp[(size_t)r * N] = acc[i][j][r];
        }
}

// Per (b,h,seg): M_seg[d][v] = sum_i sk[i,d]*v[i,v]; zsum[d] = sum_i sk[i,d]
__global__ __launch_bounds__(256) void seg_stats(
    const float* __restrict__ kproj, const float* __restrict__ vproj,
    float* __restrict__ Mseg, float* __restrict__ zsum)
{
    __shared__ float ks[64][68];
    __shared__ float vs[64][68];
    const int idx = blockIdx.x;
    const int seg = idx & 15;
    const int bh  = idx >> 4;
    const int h   = bh & 15;
    const int b   = bh >> 4;
    const size_t base = ((size_t)b * T_ + (size_t)seg * SEG_ + (size_t)h * 32) * D_;
    const float* kt = kproj + base;
    const float* vt = vproj + base;
    const int t  = threadIdx.x;
    const int d0 = (t >> 4) * 4;
    const int v0 = (t & 15) * 4;
    const int lr = t >> 2;
    const int lc = (t & 3) * 16;
    float acc[4][4];
#pragma unroll
    for (int i = 0; i < 4; ++i)
#pragma unroll
        for (int j = 0; j < 4; ++j) acc[i][j] = 0.f;
    float zacc = 0.f;

    for (int c0 = 0; c0 < SEG_; c0 += 64) {
        __syncthreads();
#pragma unroll
        for (int u = 0; u < 4; ++u) {
            float4 kv = *(const float4*)(kt + (size_t)(c0 + lr) * 64 + lc + u * 4);
            float4 vv = *(const float4*)(vt + (size_t)(c0 + lr) * 64 + lc + u * 4);
            ks[lr][lc + u * 4 + 0] = elu1(kv.x);
            ks[lr][lc + u * 4 + 1] = elu1(kv.y);
            ks[lr][lc + u * 4 + 2] = elu1(kv.z);
            ks[lr][lc + u * 4 + 3] = elu1(kv.w);
            vs[lr][lc + u * 4 + 0] = vv.x;
            vs[lr][lc + u * 4 + 1] = vv.y;
            vs[lr][lc + u * 4 + 2] = vv.z;
            vs[lr][lc + u * 4 + 3] = vv.w;
        }
        __syncthreads();
#pragma unroll 8
        for (int i = 0; i < 64; ++i) {
            float a0 = ks[i][d0 + 0], a1 = ks[i][d0 + 1];
            float a2 = ks[i][d0 + 2], a3 = ks[i][d0 + 3];
            float b0 = vs[i][v0 + 0], b1 = vs[i][v0 + 1];
            float b2 = vs[i][v0 + 2], b3 = vs[i][v0 + 3];
            acc[0][0] += a0 * b0; acc[0][1] += a0 * b1; acc[0][2] += a0 * b2; acc[0][3] += a0 * b3;
            acc[1][0] += a1 * b0; acc[1][1] += a1 * b1; acc[1][2] += a1 * b2; acc[1][3] += a1 * b3;
            acc[2][0] += a2 * b0; acc[2][1] += a2 * b1; acc[2][2] += a2 * b2; acc[2][3] += a2 * b3;
            acc[3][0] += a3 * b0; acc[3][1] += a3 * b1; acc[3][2] += a3 * b2; acc[3][3] += a3 * b3;
        }
        if (t < 64) {
#pragma unroll 8
            for (int i = 0; i < 64; ++i) zacc += ks[i][t];
        }
    }
    float* Mout = Mseg + (size_t)idx * 4096;
#pragma unroll
    for (int i = 0; i < 4; ++i)
        *(float4*)(Mout + (size_t)(d0 + i) * 64 + v0) =
            make_float4(acc[i][0], acc[i][1], acc[i][2], acc[i][3]);
    if (t < 64) zsum[(size_t)idx * 64 + t] = zacc;
}

// Per (b,h): in-place exclusive prefix of M, inclusive prefix of z.
__global__ __launch_bounds__(256) void prefix_scan(
    float* __restrict__ M, float* __restrict__ z)
{
    const int bh = blockIdx.x;
    const int t  = threadIdx.x;
    float run[16];
#pragma unroll
    for (int u = 0; u < 16; ++u) run[u] = 0.f;
    float runz = 0.f;
    for (int seg = 0; seg < NSEG_; ++seg) {
        const size_t o = ((size_t)bh * NSEG_ + seg) * 4096 + (size_t)t * 16;
#pragma unroll
        for (int u = 0; u < 16; u += 4) {
            float4 m = *(const float4*)(M + o + u);
            *(float4*)(M + o + u) = make_float4(run[u], run[u+1], run[u+2], run[u+3]);
            run[u] += m.x; run[u+1] += m.y; run[u+2] += m.z; run[u+3] += m.w;
        }
        if (t < 64) {
            const size_t oz = ((size_t)bh * NSEG_ + seg) * 64 + t;
            runz += z[oz];
            z[oz] = runz;
        }
    }
}

// Per (b,h,seg,64-row q-chunk): flash attention + memory read + gate.
// Writes att as bf16 hi/lo (input to the out-GEMM).
__global__ __launch_bounds__(256) void attn_kernel(
    const float* __restrict__ qproj, const float* __restrict__ kproj,
    const float* __restrict__ vproj, const float* __restrict__ memb,
    const float* __restrict__ Zaf, const float* __restrict__ betas,
    unsigned short* __restrict__ ath, unsigned short* __restrict__ atl)
{
    __shared__ float qs[64][68];
    __shared__ float ks[64][68];   // mem tile, then k chunks, then reused for P
    __shared__ float vs[64][68];
    __shared__ float Zsh[64];
    __shared__ float gsh[64];
    const int idx  = blockIdx.x;
    const int qc   = idx & 7;
    const int rest = idx >> 3;
    const int seg  = rest & 15;
    const int bh   = rest >> 4;
    const int h    = bh & 15;
    const int b    = bh >> 4;
    const size_t base = ((size_t)b * T_ + (size_t)seg * SEG_ + (size_t)h * 32) * D_;
    const float* qt = qproj + base + (size_t)qc * 64 * 64;
    const float* kt = kproj + base;
    const float* vt = vproj + base;
    const float* mb = memb + (size_t)rest * 4096;
    const float* Zp = Zaf + (size_t)rest * 64;
    const int t  = threadIdx.x;
    const int r  = t >> 2;    // q-row 0..63
    const int p  = t & 3;     // quarter: score cols 4j+p; v-dims [p*16,p*16+16)
    const int lr = t >> 2;
    const int lc = (t & 3) * 16;

#pragma unroll
    for (int u = 0; u < 4; ++u) {
        *(float4*)&qs[lr][lc + u * 4] = *(const float4*)(qt + (size_t)lr * 64 + lc + u * 4);
        *(float4*)&ks[lr][lc + u * 4] = *(const float4*)(mb + (size_t)lr * 64 + lc + u * 4);
    }
    if (t < 64) {
        Zsh[t] = Zp[t];
        gsh[t] = 1.f / (1.f + __expf(-betas[h * 64 + t]));
    }
    __syncthreads();

    float num[16];
#pragma unroll
    for (int u = 0; u < 16; ++u) num[u] = 0.f;
    float rowsum = 0.f;
#pragma unroll 4
    for (int d = 0; d < 64; ++d) {
        float sq = elu1(qs[r][d]);
        rowsum += sq;
#pragma unroll
        for (int u = 0; u < 4; ++u) {
            float4 mm = *(const float4*)&ks[d][p * 16 + u * 4];
            num[u*4+0] += sq * mm.x;
            num[u*4+1] += sq * mm.y;
            num[u*4+2] += sq * mm.z;
            num[u*4+3] += sq * mm.w;
        }
    }

    float o16[16];
#pragma unroll
    for (int u = 0; u < 16; ++u) o16[u] = 0.f;
    float m_r = -1e30f, l_r = 0.f;

    for (int kb = 0; kb < 8; ++kb) {
        __syncthreads();
#pragma unroll
        for (int u = 0; u < 4; ++u) {
            *(float4*)&ks[lr][lc + u * 4] =
                *(const float4*)(kt + (size_t)(kb * 64 + lr) * 64 + lc + u * 4);
            *(float4*)&vs[lr][lc + u * 4] =
                *(const float4*)(vt + (size_t)(kb * 64 + lr) * 64 + lc + u * 4);
        }
        __syncthreads();

        // scores: thread owns k-rows 4j+p -> the 4 p-addresses land on bank
        // quads {0,4,8,12}: conflict-free (was 4-way at p*16+j).
        float s[16];
#pragma unroll
        for (int j = 0; j < 16; ++j) s[j] = 0.f;
#pragma unroll 4
        for (int d4 = 0; d4 < 16; ++d4) {
            float4 q4 = *(const float4*)&qs[r][d4 * 4];
#pragma unroll
            for (int j = 0; j < 16; ++j) {
                float4 k4 = *(const float4*)&ks[4 * j + p][d4 * 4];
                s[j] += q4.x * k4.x + q4.y * k4.y + q4.z * k4.z + q4.w * k4.w;
            }
        }
        float mx = -1e30f;
#pragma unroll
        for (int j = 0; j < 16; ++j) { s[j] *= 0.125f; mx = fmaxf(mx, s[j]); }
        mx = fmaxf(mx, __shfl_xor(mx, 1, 4));
        mx = fmaxf(mx, __shfl_xor(mx, 2, 4));
        const float mnew = fmaxf(m_r, mx);
        const float corr = __expf(m_r - mnew);
        float pv[16];
        float psum = 0.f;
#pragma unroll
        for (int j = 0; j < 16; ++j) { pv[j] = __expf(s[j] - mnew); psum += pv[j]; }
        psum += __shfl_xor(psum, 1, 4);
        psum += __shfl_xor(psum, 2, 4);
        l_r = l_r * corr + psum;
        m_r = mnew;
#pragma unroll
        for (int u = 0; u < 16; ++u) o16[u] *= corr;

        __syncthreads();
#pragma unroll
        for (int j = 0; j < 16; ++j)
            ks[r][4 * j + p] = pv[j];   // banks 4r+4j+p: 2-way max (free)
        __syncthreads();
#pragma unroll 4
        for (int i4 = 0; i4 < 16; ++i4) {
            float4 pq = *(const float4*)&ks[r][i4 * 4];
            float pw[4] = {pq.x, pq.y, pq.z, pq.w};
#pragma unroll
            for (int c = 0; c < 4; ++c) {
                const int i = i4 * 4 + c;
                const float w = pw[c];
#pragma unroll
                for (int u = 0; u < 4; ++u) {
                    float4 vv = *(const float4*)&vs[i][p * 16 + u * 4];
                    o16[u*4+0] += w * vv.x;
                    o16[u*4+1] += w * vv.y;
                    o16[u*4+2] += w * vv.z;
                    o16[u*4+3] += w * vv.w;
                }
            }
        }
    }

    const float inv_l  = 1.f / l_r;
    const float inv_rs = 1.f / rowsum;
    const size_t obase = base + (size_t)(qc * 64 + r) * 64 + p * 16;
#pragma unroll
    for (int u = 0; u < 4; ++u) {
        ushort4 hv, lv;
        float res[4];
#pragma unroll
        for (int c = 0; c < 4; ++c) {
            const int vv = p * 16 + u * 4 + c;
            const float adot = o16[u*4+c] * inv_l;
            const float amem = num[u*4+c] * inv_rs / Zsh[vv];
            const float g = gsh[vv];
            res[c] = g * amem + (1.f - g) * adot;
        }
        hv.x = f2bf(res[0]); lv.x = f2bf(res[0] - bf2f(hv.x));
        hv.y = f2bf(res[1]); lv.y = f2bf(res[1] - bf2f(hv.y));
        hv.z = f2bf(res[2]); lv.z = f2bf(res[2] - bf2f(hv.z));
        hv.w = f2bf(res[3]); lv.w = f2bf(res[3] - bf2f(hv.w));
        *(ushort4*)(ath + obase + u * 4) = hv;
        *(ushort4*)(atl + obase + u * 4) = lv;
    }
}

extern "C" void kernel_launch(void* const* d_in, const int* in_sizes, int n_in,
                              void* d_out, int out_size, void* d_ws, size_t ws_size,
                              hipStream_t stream) {
    const float* x     = (const float*)d_in[0];
    const float* Wq    = (const float*)d_in[1];
    const float* Wk    = (const float*)d_in[2];
    const float* Wv    = (const float*)d_in[3];
    const float* Wout  = (const float*)d_in[4];
    const float* betas = (const float*)d_in[5];
    float* out = (float*)d_out;
    (void)d_ws; (void)ws_size;

    float *q, *k, *v, *M, *z;
    unsigned short *xh, *xl, *ath, *atl, *wqh, *wql, *wkh, *wkl, *wvh, *wvl, *woh, *wol;
    hipGetSymbolAddress((void**)&q,   HIP_SYMBOL(g_q));
    hipGetSymbolAddress((void**)&k,   HIP_SYMBOL(g_k));
    hipGetSymbolAddress((void**)&v,   HIP_SYMBOL(g_v));
    hipGetSymbolAddress((void**)&M,   HIP_SYMBOL(g_M));
    hipGetSymbolAddress((void**)&z,   HIP_SYMBOL(g_z));
    hipGetSymbolAddress((void**)&xh,  HIP_SYMBOL(g_xh));
    hipGetSymbolAddress((void**)&xl,  HIP_SYMBOL(g_xl));
    hipGetSymbolAddress((void**)&ath, HIP_SYMBOL(g_ath));
    hipGetSymbolAddress((void**)&atl, HIP_SYMBOL(g_atl));
    hipGetSymbolAddress((void**)&wqh, HIP_SYMBOL(g_wqh));
    hipGetSymbolAddress((void**)&wql, HIP_SYMBOL(g_wql));
    hipGetSymbolAddress((void**)&wkh, HIP_SYMBOL(g_wkh));
    hipGetSymbolAddress((void**)&wkl, HIP_SYMBOL(g_wkl));
    hipGetSymbolAddress((void**)&wvh, HIP_SYMBOL(g_wvh));
    hipGetSymbolAddress((void**)&wvl, HIP_SYMBOL(g_wvl));
    hipGetSymbolAddress((void**)&woh, HIP_SYMBOL(g_woh));
    hipGetSymbolAddress((void**)&wol, HIP_SYMBOL(g_wol));

    const int nX = (int)NPROJ, nW = (int)NW;
    split_bf16<<<nX / 1024, 256, 0, stream>>>(x,    xh,  xl,  nX);
    split_bf16<<<nW / 1024, 256, 0, stream>>>(Wq,   wqh, wql, nW);
    split_bf16<<<nW / 1024, 256, 0, stream>>>(Wk,   wkh, wkl, nW);
    split_bf16<<<nW / 1024, 256, 0, stream>>>(Wv,   wvh, wvl, nW);
    split_bf16<<<nW / 1024, 256, 0, stream>>>(Wout, woh, wol, nW);

    dim3 gg(D_ / 128, BT_ / 128);   // (8, 128)
    gemm_bt_split<<<gg, 256, 0, stream>>>(xh, xl, wqh, wql, q, BT_, D_, D_);
    gemm_bt_split<<<gg, 256, 0, stream>>>(xh, xl, wkh, wkl, k, BT_, D_, D_);
    gemm_bt_split<<<gg, 256, 0, stream>>>(xh, xl, wvh, wvl, v, BT_, D_, D_);
    seg_stats<<<B_ * H_ * NSEG_, 256, 0, stream>>>(k, v, M, z);
    prefix_scan<<<B_ * H_, 256, 0, stream>>>(M, z);
    attn_kernel<<<B_ * H_ * NSEG_ * 8, 256, 0, stream>>>(q, k, v, M, z, betas, ath, atl);
    gemm_bt_split<<<gg, 256, 0, stream>>>(ath, atl, woh, wol, out, BT_, D_, D_);
}

// Round 4
// 1020.899 us; speedup vs baseline: 3.1688x; 1.6423x over previous
//
#include <hip/hip_runtime.h>

// CompressiveMemory — round 4: MFMA attention.
//  * attn was LDS-BW-bound (73 GB LDS reads ~= 1060 us @ 69 TB/s ~= measured
//    975 us). Rewrite QK^T, P@V, sq@mem on 16x16x32 bf16 MFMA: fragments read
//    once per tile -> ~13x less LDS traffic. Softmax/accum stay fp32.
//  * seg_stats additionally emits V^T as bf16 (g_vt) so attn can stage the
//    PV B-operand (needs V transposed) with clean vectorized copies.
//  * P C-layout -> A-layout via LDS round-trip; each wave touches only its
//    own 16 rows (no barrier; DS ops in-order per wave).
//  * GEMMs stay split-bf16 (3-MFMA, ~fp32 accurate) from round 3.
// View insight (unchanged): each (b,seg,h) (512x64) tile is the CONTIGUOUS
// 32x1024 row-block at row b*8192+seg*512+h*32; output reshape is inverse.

#define H_ 16
#define SEG_ 512
#define NSEG_ 16
#define B_ 2
#define T_ 8192
#define D_ 1024
#define BT_ 16384

#define NPROJ ((size_t)BT_ * D_)   // 16,777,216
#define NW ((size_t)D_ * D_)       // 1,048,576

__device__ float g_q[NPROJ];
__device__ float g_k[NPROJ];
__device__ float g_v[NPROJ];
__device__ unsigned short g_vt[(size_t)512 * 64 * 512];   // per-tile V^T, bf16
__device__ unsigned short g_xh[NPROJ], g_xl[NPROJ];
__device__ unsigned short g_ath[NPROJ], g_atl[NPROJ];
__device__ unsigned short g_wqh[NW], g_wql[NW];
__device__ unsigned short g_wkh[NW], g_wkl[NW];
__device__ unsigned short g_wvh[NW], g_wvl[NW];
__device__ unsigned short g_woh[NW], g_wol[NW];
__device__ float g_M[(size_t)512 * 4096];
__device__ float g_z[(size_t)512 * 64];

typedef __attribute__((ext_vector_type(8))) short short8;
typedef __attribute__((ext_vector_type(8))) unsigned short ushort8;
typedef __attribute__((ext_vector_type(4))) float f32x4;

__device__ __forceinline__ float elu1(float x) {
    return x > 0.f ? x + 1.f : __expf(x);
}
__device__ __forceinline__ unsigned short f2bf(float x) {
    unsigned u = __float_as_uint(x);
    u += 0x7fffu + ((u >> 16) & 1u);           // RNE
    return (unsigned short)(u >> 16);
}
__device__ __forceinline__ float bf2f(unsigned short h) {
    return __uint_as_float((unsigned)h << 16);
}
__device__ __forceinline__ void load_lds16(const unsigned short* g, unsigned short* l) {
    __builtin_amdgcn_global_load_lds(
        (const __attribute__((address_space(1))) unsigned int*)g,
        (__attribute__((address_space(3))) unsigned int*)l, 16, 0, 0);
}

// fp32 -> (bf16 hi, bf16 lo). 4 elems/thread.
__global__ __launch_bounds__(256) void split_bf16(
    const float* __restrict__ in, unsigned short* __restrict__ hi,
    unsigned short* __restrict__ lo, int n)
{
    int i = (blockIdx.x * 256 + threadIdx.x) * 4;
    if (i >= n) return;
    float4 x = *(const float4*)(in + i);
    ushort4 h, l;
    h.x = f2bf(x.x); l.x = f2bf(x.x - bf2f(h.x));
    h.y = f2bf(x.y); l.y = f2bf(x.y - bf2f(h.y));
    h.z = f2bf(x.z); l.z = f2bf(x.z - bf2f(h.z));
    h.w = f2bf(x.w); l.w = f2bf(x.w - bf2f(h.w));
    *(ushort4*)(hi + i) = h;
    *(ushort4*)(lo + i) = l;
}

// C[m,n] = sum_k A[m,k]*B[n,k], A,B bf16 hi/lo pairs; C fp32. (round 3)
#define BK 32
__global__ __launch_bounds__(256) void gemm_bt_split(
    const unsigned short* __restrict__ Ah, const unsigned short* __restrict__ Al,
    const unsigned short* __restrict__ Bh, const unsigned short* __restrict__ Bl,
    float* __restrict__ C, int M, int N, int K)
{
    __shared__ unsigned short sAh[128 * BK], sAl[128 * BK];
    __shared__ unsigned short sBh[128 * BK], sBl[128 * BK];
    const int t = threadIdx.x;
    const int lane = t & 63, wave = t >> 6;
    const int m0 = blockIdx.y * 128, n0 = blockIdx.x * 128;
    const int wm = (wave & 1) * 64, wn = (wave >> 1) * 64;
    const int srow = wave * 32 + (lane >> 2);
    const int scol = (lane & 3) * 8;
    const int fr = lane & 15, fq = (lane >> 4) * 8;

    f32x4 acc[4][4];
#pragma unroll
    for (int i = 0; i < 4; ++i)
#pragma unroll
        for (int j = 0; j < 4; ++j) acc[i][j] = (f32x4)0.f;

    for (int k0 = 0; k0 < K; k0 += BK) {
        __syncthreads();
#pragma unroll
        for (int i = 0; i < 2; ++i) {
            const size_t ga = (size_t)(m0 + srow + i * 16) * K + k0 + scol;
            const size_t gb = (size_t)(n0 + srow + i * 16) * K + k0 + scol;
            const int lb = (wave * 32 + i * 16) * BK;
            load_lds16(Ah + ga, &sAh[lb]);
            load_lds16(Al + ga, &sAl[lb]);
            load_lds16(Bh + gb, &sBh[lb]);
            load_lds16(Bl + gb, &sBl[lb]);
        }
        __syncthreads();
        short8 ah[4], al[4], bh[4], bl[4];
#pragma unroll
        for (int i = 0; i < 4; ++i) {
            ah[i] = *(const short8*)&sAh[(wm + i * 16 + fr) * BK + fq];
            al[i] = *(const short8*)&sAl[(wm + i * 16 + fr) * BK + fq];
            bh[i] = *(const short8*)&sBh[(wn + i * 16 + fr) * BK + fq];
            bl[i] = *(const short8*)&sBl[(wn + i * 16 + fr) * BK + fq];
        }
#pragma unroll
        for (int i = 0; i < 4; ++i)
#pragma unroll
            for (int j = 0; j < 4; ++j) {
                acc[i][j] = __builtin_amdgcn_mfma_f32_16x16x32_bf16(ah[i], bh[j], acc[i][j], 0, 0, 0);
                acc[i][j] = __builtin_amdgcn_mfma_f32_16x16x32_bf16(al[i], bh[j], acc[i][j], 0, 0, 0);
                acc[i][j] = __builtin_amdgcn_mfma_f32_16x16x32_bf16(ah[i], bl[j], acc[i][j], 0, 0, 0);
            }
    }
    const int ccol = lane & 15, crow = (lane >> 4) * 4;
#pragma unroll
    for (int i = 0; i < 4; ++i)
#pragma unroll
        for (int j = 0; j < 4; ++j) {
            float* cp = C + (size_t)(m0 + wm + i * 16 + crow) * N + (n0 + wn + j * 16 + ccol);
#pragma unroll
            for (int r = 0; r < 4; ++r) cp[(size_t)r * N] = acc[i][j][r];
        }
}

// Per (b,h,seg): M_seg, zsum, and bf16 V^T tile for attn.
__global__ __launch_bounds__(256) void seg_stats(
    const float* __restrict__ kproj, const float* __restrict__ vproj,
    float* __restrict__ Mseg, float* __restrict__ zsum,
    unsigned short* __restrict__ vtg)
{
    __shared__ float ks[64][68];
    __shared__ float vs[64][68];
    const int idx = blockIdx.x;
    const int seg = idx & 15;
    const int bh  = idx >> 4;
    const int h   = bh & 15;
    const int b   = bh >> 4;
    const size_t base = ((size_t)b * T_ + (size_t)seg * SEG_ + (size_t)h * 32) * D_;
    const float* kt = kproj + base;
    const float* vt = vproj + base;
    const int t  = threadIdx.x;
    const int d0 = (t >> 4) * 4;
    const int v0 = (t & 15) * 4;
    const int lr = t >> 2;
    const int lc = (t & 3) * 16;
    float acc[4][4];
#pragma unroll
    for (int i = 0; i < 4; ++i)
#pragma unroll
        for (int j = 0; j < 4; ++j) acc[i][j] = 0.f;
    float zacc = 0.f;

    for (int c0 = 0; c0 < SEG_; c0 += 64) {
        __syncthreads();
#pragma unroll
        for (int u = 0; u < 4; ++u) {
            float4 kv = *(const float4*)(kt + (size_t)(c0 + lr) * 64 + lc + u * 4);
            float4 vv = *(const float4*)(vt + (size_t)(c0 + lr) * 64 + lc + u * 4);
            ks[lr][lc + u * 4 + 0] = elu1(kv.x);
            ks[lr][lc + u * 4 + 1] = elu1(kv.y);
            ks[lr][lc + u * 4 + 2] = elu1(kv.z);
            ks[lr][lc + u * 4 + 3] = elu1(kv.w);
            vs[lr][lc + u * 4 + 0] = vv.x;
            vs[lr][lc + u * 4 + 1] = vv.y;
            vs[lr][lc + u * 4 + 2] = vv.z;
            vs[lr][lc + u * 4 + 3] = vv.w;
        }
        __syncthreads();
#pragma unroll 8
        for (int i = 0; i < 64; ++i) {
            float a0 = ks[i][d0 + 0], a1 = ks[i][d0 + 1];
            float a2 = ks[i][d0 + 2], a3 = ks[i][d0 + 3];
            float b0 = vs[i][v0 + 0], b1 = vs[i][v0 + 1];
            float b2 = vs[i][v0 + 2], b3 = vs[i][v0 + 3];
            acc[0][0] += a0 * b0; acc[0][1] += a0 * b1; acc[0][2] += a0 * b2; acc[0][3] += a0 * b3;
            acc[1][0] += a1 * b0; acc[1][1] += a1 * b1; acc[1][2] += a1 * b2; acc[1][3] += a1 * b3;
            acc[2][0] += a2 * b0; acc[2][1] += a2 * b1; acc[2][2] += a2 * b2; acc[2][3] += a2 * b3;
            acc[3][0] += a3 * b0; acc[3][1] += a3 * b1; acc[3][2] += a3 * b2; acc[3][3] += a3 * b3;
        }
        if (t < 64) {
#pragma unroll 8
            for (int i = 0; i < 64; ++i) zacc += ks[i][t];
        }
        // transposed bf16 v out: row = v-dim (lr), cols = time (c0+lc..)
        {
            ushort8 w0, w1;
#pragma unroll
            for (int i = 0; i < 8; ++i) w0[i] = f2bf(vs[lc + i][lr]);
#pragma unroll
            for (int i = 0; i < 8; ++i) w1[i] = f2bf(vs[lc + 8 + i][lr]);
            unsigned short* vo = vtg + ((size_t)idx * 64 + lr) * 512 + c0 + lc;
            *(ushort8*)vo       = w0;
            *(ushort8*)(vo + 8) = w1;
        }
    }
    float* Mout = Mseg + (size_t)idx * 4096;
#pragma unroll
    for (int i = 0; i < 4; ++i)
        *(float4*)(Mout + (size_t)(d0 + i) * 64 + v0) =
            make_float4(acc[i][0], acc[i][1], acc[i][2], acc[i][3]);
    if (t < 64) zsum[(size_t)idx * 64 + t] = zacc;
}

// Per (b,h): in-place exclusive prefix of M, inclusive prefix of z.
__global__ __launch_bounds__(256) void prefix_scan(
    float* __restrict__ M, float* __restrict__ z)
{
    const int bh = blockIdx.x;
    const int t  = threadIdx.x;
    float run[16];
#pragma unroll
    for (int u = 0; u < 16; ++u) run[u] = 0.f;
    float runz = 0.f;
    for (int seg = 0; seg < NSEG_; ++seg) {
        const size_t o = ((size_t)bh * NSEG_ + seg) * 4096 + (size_t)t * 16;
#pragma unroll
        for (int u = 0; u < 16; u += 4) {
            float4 m = *(const float4*)(M + o + u);
            *(float4*)(M + o + u) = make_float4(run[u], run[u+1], run[u+2], run[u+3]);
            run[u] += m.x; run[u+1] += m.y; run[u+2] += m.z; run[u+3] += m.w;
        }
        if (t < 64) {
            const size_t oz = ((size_t)bh * NSEG_ + seg) * 64 + t;
            runz += z[oz];
            z[oz] = runz;
        }
    }
}

// MFMA flash attention per (b,h,seg,64-row q-chunk). 4 waves; wave owns 16
// q-rows. QK^T / P@V / sq@mem on 16x16x32 bf16 MFMA; softmax+accum fp32.
__global__ __launch_bounds__(256) void attn_mfma(
    const float* __restrict__ qproj, const float* __restrict__ kproj,
    const unsigned short* __restrict__ vtg, const float* __restrict__ memb,
    const float* __restrict__ Zaf, const float* __restrict__ betas,
    unsigned short* __restrict__ ath, unsigned short* __restrict__ atl)
{
    __shared__ unsigned short sm_k[64 * 72];   // k bf16 ; epilogue att_hi
    __shared__ unsigned short sm_v[64 * 72];   // V^T bf16 ; epilogue att_lo
    __shared__ unsigned short sm_p[64 * 72];   // mem^T bf16, then P bf16
    __shared__ float Zsh[64], gsh[64];

    const int idx  = blockIdx.x;
    const int qc   = idx & 7;
    const int rest = idx >> 3;
    const int seg  = rest & 15;
    const int bh   = rest >> 4;
    const int h    = bh & 15;
    const int b    = bh >> 4;
    const size_t base = ((size_t)b * T_ + (size_t)seg * SEG_ + (size_t)h * 32) * D_;

    const int t    = threadIdx.x;
    const int lane = t & 63;
    const int w    = t >> 6;
    const int c16  = lane & 15;
    const int g4   = lane >> 4;
    const int lr   = t >> 2;          // staging row 0..63
    const int lc   = (t & 3) * 16;    // staging col

    const float* qt = qproj + base + (size_t)qc * 4096;
    const float* kt = kproj + base;
    const unsigned short* vt = vtg + (size_t)rest * (64 * 512);
    const float* mb = memb + (size_t)rest * 4096;

    if (t < 64) {
        Zsh[t] = Zaf[(size_t)rest * 64 + t];
        gsh[t] = 1.f / (1.f + __expf(-betas[h * 64 + t]));
    }

    // q fragments (A-layout: m = w*16+c16, k = g4*8 + ks*32 + j), sq, rowsum
    short8 qh[2], sqh[2];
    float rowsum = 0.f;
#pragma unroll
    for (int ks = 0; ks < 2; ++ks) {
        const float* qp = qt + (size_t)(w * 16 + c16) * 64 + g4 * 8 + ks * 32;
        float4 qa = *(const float4*)qp;
        float4 qb = *(const float4*)(qp + 4);
        float qv[8] = {qa.x, qa.y, qa.z, qa.w, qb.x, qb.y, qb.z, qb.w};
        short8 qf, sf;
#pragma unroll
        for (int j = 0; j < 8; ++j) {
            float e = elu1(qv[j]);
            rowsum += e;
            qf[j] = (short)f2bf(qv[j]);
            sf[j] = (short)f2bf(e);
        }
        qh[ks] = qf; sqh[ks] = sf;
    }
    rowsum += __shfl_xor(rowsum, 16);
    rowsum += __shfl_xor(rowsum, 32);

    // stage mem^T (bf16) into sm_p
    {
        const float* mp = mb + (size_t)lr * 64 + lc;
#pragma unroll
        for (int u = 0; u < 4; ++u) {
            float4 m4 = *(const float4*)(mp + u * 4);
            sm_p[(lc + u * 4 + 0) * 72 + lr] = f2bf(m4.x);
            sm_p[(lc + u * 4 + 1) * 72 + lr] = f2bf(m4.y);
            sm_p[(lc + u * 4 + 2) * 72 + lr] = f2bf(m4.z);
            sm_p[(lc + u * 4 + 3) * 72 + lr] = f2bf(m4.w);
        }
    }
    __syncthreads();

    // num = sq @ mem  (B-operand = mem^T[v][d])
    f32x4 numf[4];
#pragma unroll
    for (int nf = 0; nf < 4; ++nf) numf[nf] = (f32x4)0.f;
#pragma unroll
    for (int ks = 0; ks < 2; ++ks)
#pragma unroll
        for (int nf = 0; nf < 4; ++nf) {
            short8 bm = *(const short8*)&sm_p[(nf * 16 + c16) * 72 + g4 * 8 + ks * 32];
            numf[nf] = __builtin_amdgcn_mfma_f32_16x16x32_bf16(sqh[ks], bm, numf[nf], 0, 0, 0);
        }

    f32x4 o[4];
#pragma unroll
    for (int nf = 0; nf < 4; ++nf) o[nf] = (f32x4)0.f;
    float mrow[4] = {-1e30f, -1e30f, -1e30f, -1e30f};
    float lrow[4] = {0.f, 0.f, 0.f, 0.f};

    for (int kb = 0; kb < 8; ++kb) {
        __syncthreads();
        {   // stage k (fp32->bf16) and V^T (already bf16)
            const float* kp = kt + (size_t)(kb * 64 + lr) * 64 + lc;
            float4 k0 = *(const float4*)kp;
            float4 k1 = *(const float4*)(kp + 4);
            float4 k2 = *(const float4*)(kp + 8);
            float4 k3 = *(const float4*)(kp + 12);
            ushort8 p0, p1;
            p0[0] = f2bf(k0.x); p0[1] = f2bf(k0.y); p0[2] = f2bf(k0.z); p0[3] = f2bf(k0.w);
            p0[4] = f2bf(k1.x); p0[5] = f2bf(k1.y); p0[6] = f2bf(k1.z); p0[7] = f2bf(k1.w);
            p1[0] = f2bf(k2.x); p1[1] = f2bf(k2.y); p1[2] = f2bf(k2.z); p1[3] = f2bf(k2.w);
            p1[4] = f2bf(k3.x); p1[5] = f2bf(k3.y); p1[6] = f2bf(k3.z); p1[7] = f2bf(k3.w);
            *(ushort8*)&sm_k[lr * 72 + lc]     = p0;
            *(ushort8*)&sm_k[lr * 72 + lc + 8] = p1;
            const unsigned short* vp = vt + (size_t)lr * 512 + kb * 64 + lc;
            *(ushort8*)&sm_v[lr * 72 + lc]     = *(const ushort8*)vp;
            *(ushort8*)&sm_v[lr * 72 + lc + 8] = *(const ushort8*)(vp + 8);
        }
        __syncthreads();

        // scores S = Q @ K^T
        f32x4 s[4];
#pragma unroll
        for (int nf = 0; nf < 4; ++nf) s[nf] = (f32x4)0.f;
#pragma unroll
        for (int ks = 0; ks < 2; ++ks)
#pragma unroll
            for (int nf = 0; nf < 4; ++nf) {
                short8 bk = *(const short8*)&sm_k[(nf * 16 + c16) * 72 + g4 * 8 + ks * 32];
                s[nf] = __builtin_amdgcn_mfma_f32_16x16x32_bf16(qh[ks], bk, s[nf], 0, 0, 0);
            }
#pragma unroll
        for (int nf = 0; nf < 4; ++nf) s[nf] *= 0.125f;

        // online softmax; C-layout row r lives in the 16 lanes of group g4
        float corr[4];
#pragma unroll
        for (int r = 0; r < 4; ++r) {
            float mx = fmaxf(fmaxf(s[0][r], s[1][r]), fmaxf(s[2][r], s[3][r]));
            mx = fmaxf(mx, __shfl_xor(mx, 1));
            mx = fmaxf(mx, __shfl_xor(mx, 2));
            mx = fmaxf(mx, __shfl_xor(mx, 4));
            mx = fmaxf(mx, __shfl_xor(mx, 8));
            float mnew = fmaxf(mrow[r], mx);
            corr[r] = __expf(mrow[r] - mnew);
            mrow[r] = mnew;
        }
#pragma unroll
        for (int nf = 0; nf < 4; ++nf)
#pragma unroll
            for (int r = 0; r < 4; ++r)
                s[nf][r] = __expf(s[nf][r] - mrow[r]);
#pragma unroll
        for (int r = 0; r < 4; ++r) {
            float ps = s[0][r] + s[1][r] + s[2][r] + s[3][r];
            ps += __shfl_xor(ps, 1);
            ps += __shfl_xor(ps, 2);
            ps += __shfl_xor(ps, 4);
            ps += __shfl_xor(ps, 8);
            lrow[r] = lrow[r] * corr[r] + ps;
        }
#pragma unroll
        for (int nf = 0; nf < 4; ++nf)
#pragma unroll
            for (int r = 0; r < 4; ++r) o[nf][r] *= corr[r];

        // publish P (C-layout -> A-layout). Wave touches only rows
        // [w*16, w*16+16): same-wave DS ordering, no barrier.
#pragma unroll
        for (int nf = 0; nf < 4; ++nf)
#pragma unroll
            for (int r = 0; r < 4; ++r)
                sm_p[(w * 16 + g4 * 4 + r) * 72 + nf * 16 + c16] = f2bf(s[nf][r]);

        // O += P @ V  (B-operand = V^T[v][t])
#pragma unroll
        for (int ks = 0; ks < 2; ++ks) {
            short8 pa = *(const short8*)&sm_p[(w * 16 + c16) * 72 + g4 * 8 + ks * 32];
#pragma unroll
            for (int nf = 0; nf < 4; ++nf) {
                short8 bv = *(const short8*)&sm_v[(nf * 16 + c16) * 72 + g4 * 8 + ks * 32];
                o[nf] = __builtin_amdgcn_mfma_f32_16x16x32_bf16(pa, bv, o[nf], 0, 0, 0);
            }
        }
    }

    __syncthreads();   // k/v staging done — reuse sm_k/sm_v for att hi/lo

    float rs[4], invl[4];
#pragma unroll
    for (int r = 0; r < 4; ++r) {
        rs[r]   = __shfl(rowsum, (g4 << 2) + r);   // rowsum of row w*16+g4*4+r
        invl[r] = 1.f / lrow[r];
    }
#pragma unroll
    for (int nf = 0; nf < 4; ++nf) {
        const int col = nf * 16 + c16;
        const float Zc = Zsh[col], gc = gsh[col];
        const float izc = 1.f / Zc;
#pragma unroll
        for (int r = 0; r < 4; ++r) {
            const float adot = o[nf][r] * invl[r];
            const float amem = numf[nf][r] * izc / rs[r];
            const float res  = gc * amem + (1.f - gc) * adot;
            const unsigned short hv = f2bf(res);
            const unsigned short lv = f2bf(res - bf2f(hv));
            const int row = w * 16 + g4 * 4 + r;
            sm_k[row * 72 + col] = hv;
            sm_v[row * 72 + col] = lv;
        }
    }
    __syncthreads();
    {
        const size_t ob = base + (size_t)(qc * 64 + lr) * 64 + lc;
        *(ushort8*)(ath + ob)     = *(const ushort8*)&sm_k[lr * 72 + lc];
        *(ushort8*)(ath + ob + 8) = *(const ushort8*)&sm_k[lr * 72 + lc + 8];
        *(ushort8*)(atl + ob)     = *(const ushort8*)&sm_v[lr * 72 + lc];
        *(ushort8*)(atl + ob + 8) = *(const ushort8*)&sm_v[lr * 72 + lc + 8];
    }
}

extern "C" void kernel_launch(void* const* d_in, const int* in_sizes, int n_in,
                              void* d_out, int out_size, void* d_ws, size_t ws_size,
                              hipStream_t stream) {
    const float* x     = (const float*)d_in[0];
    const float* Wq    = (const float*)d_in[1];
    const float* Wk    = (const float*)d_in[2];
    const float* Wv    = (const float*)d_in[3];
    const float* Wout  = (const float*)d_in[4];
    const float* betas = (const float*)d_in[5];
    float* out = (float*)d_out;
    (void)d_ws; (void)ws_size;

    float *q, *k, *v, *M, *z;
    unsigned short *vt, *xh, *xl, *ath, *atl, *wqh, *wql, *wkh, *wkl, *wvh, *wvl, *woh, *wol;
    hipGetSymbolAddress((void**)&q,   HIP_SYMBOL(g_q));
    hipGetSymbolAddress((void**)&k,   HIP_SYMBOL(g_k));
    hipGetSymbolAddress((void**)&v,   HIP_SYMBOL(g_v));
    hipGetSymbolAddress((void**)&M,   HIP_SYMBOL(g_M));
    hipGetSymbolAddress((void**)&z,   HIP_SYMBOL(g_z));
    hipGetSymbolAddress((void**)&vt,  HIP_SYMBOL(g_vt));
    hipGetSymbolAddress((void**)&xh,  HIP_SYMBOL(g_xh));
    hipGetSymbolAddress((void**)&xl,  HIP_SYMBOL(g_xl));
    hipGetSymbolAddress((void**)&ath, HIP_SYMBOL(g_ath));
    hipGetSymbolAddress((void**)&atl, HIP_SYMBOL(g_atl));
    hipGetSymbolAddress((void**)&wqh, HIP_SYMBOL(g_wqh));
    hipGetSymbolAddress((void**)&wql, HIP_SYMBOL(g_wql));
    hipGetSymbolAddress((void**)&wkh, HIP_SYMBOL(g_wkh));
    hipGetSymbolAddress((void**)&wkl, HIP_SYMBOL(g_wkl));
    hipGetSymbolAddress((void**)&wvh, HIP_SYMBOL(g_wvh));
    hipGetSymbolAddress((void**)&wvl, HIP_SYMBOL(g_wvl));
    hipGetSymbolAddress((void**)&woh, HIP_SYMBOL(g_woh));
    hipGetSymbolAddress((void**)&wol, HIP_SYMBOL(g_wol));

    const int nX = (int)NPROJ, nW = (int)NW;
    split_bf16<<<nX / 1024, 256, 0, stream>>>(x,    xh,  xl,  nX);
    split_bf16<<<nW / 1024, 256, 0, stream>>>(Wq,   wqh, wql, nW);
    split_bf16<<<nW / 1024, 256, 0, stream>>>(Wk,   wkh, wkl, nW);
    split_bf16<<<nW / 1024, 256, 0, stream>>>(Wv,   wvh, wvl, nW);
    split_bf16<<<nW / 1024, 256, 0, stream>>>(Wout, woh, wol, nW);

    dim3 gg(D_ / 128, BT_ / 128);   // (8, 128)
    gemm_bt_split<<<gg, 256, 0, stream>>>(xh, xl, wqh, wql, q, BT_, D_, D_);
    gemm_bt_split<<<gg, 256, 0, stream>>>(xh, xl, wkh, wkl, k, BT_, D_, D_);
    gemm_bt_split<<<gg, 256, 0, stream>>>(xh, xl, wvh, wvl, v, BT_, D_, D_);
    seg_stats<<<B_ * H_ * NSEG_, 256, 0, stream>>>(k, v, M, z, vt);
    prefix_scan<<<B_ * H_, 256, 0, stream>>>(M, z);
    attn_mfma<<<B_ * H_ * NSEG_ * 8, 256, 0, stream>>>(q, k, vt, M, z, betas, ath, atl);
    gemm_bt_split<<<gg, 256, 0, stream>>>(ath, atl, woh, wol, out, BT_, D_, D_);
}

// Round 5
// 687.544 us; speedup vs baseline: 4.7052x; 1.4848x over previous
//
#include <hip/hip_runtime.h>

// CompressiveMemory — round 5.
//  * Fused plain-bf16 QKV projection GEMM (1 MFMA, N=3072) writing bf16
//    q/k/v directly: downstream consumes bf16 anyway, so split precision on
//    projections was wasted. 3x less MFMA work, half the q/k/v HBM traffic.
//  * XOR-swizzled LDS (p = g ^ ((row>>1)&3), applied to the global fetch
//    column so global_load_lds's fixed lane->LDS map still works): frag
//    ds_read_b128 hits the 8-words/bank floor (was 4x over).
//  * seg_stats/attn read bf16 q/k/v; attn k staging is a raw copy.
//  * Out-GEMM stays 3-MFMA split-bf16 (output accuracy), now swizzled.
// View insight (unchanged): each (b,seg,h) (512x64) tile is the CONTIGUOUS
// 32x1024 row-block at row b*8192+seg*512+h*32; output reshape is inverse.
// z is rank-degenerate; mem is an exclusive prefix of M_seg = sk^T v.

#define H_ 16
#define SEG_ 512
#define NSEG_ 16
#define B_ 2
#define T_ 8192
#define D_ 1024
#define BT_ 16384

#define NPROJ ((size_t)BT_ * D_)   // 16,777,216
#define NW ((size_t)D_ * D_)       // 1,048,576

__device__ unsigned short g_qb[NPROJ], g_kb[NPROJ], g_vb[NPROJ];   // bf16 projections
__device__ unsigned short g_xh[NPROJ];
__device__ unsigned short g_wqkv[3 * NW];                          // [Wq;Wk;Wv] bf16
__device__ unsigned short g_ath[NPROJ], g_atl[NPROJ];
__device__ unsigned short g_woh[NW], g_wol[NW];
__device__ unsigned short g_vt[(size_t)512 * 64 * 512];            // per-tile V^T bf16
__device__ float g_M[(size_t)512 * 4096];
__device__ float g_z[(size_t)512 * 64];

typedef __attribute__((ext_vector_type(8))) short short8;
typedef __attribute__((ext_vector_type(8))) unsigned short ushort8;
typedef __attribute__((ext_vector_type(4))) float f32x4;

__device__ __forceinline__ float elu1(float x) {
    return x > 0.f ? x + 1.f : __expf(x);
}
__device__ __forceinline__ unsigned short f2bf(float x) {
    unsigned u = __float_as_uint(x);
    u += 0x7fffu + ((u >> 16) & 1u);           // RNE
    return (unsigned short)(u >> 16);
}
__device__ __forceinline__ float bf2f(unsigned short h) {
    return __uint_as_float((unsigned)h << 16);
}
__device__ __forceinline__ void load_lds16(const unsigned short* g, unsigned short* l) {
    __builtin_amdgcn_global_load_lds(
        (const __attribute__((address_space(1))) unsigned int*)g,
        (__attribute__((address_space(3))) unsigned int*)l, 16, 0, 0);
}
// ushort offset of (row, 8-elem block) in a [128][32]-bf16 LDS tile, XOR-swizzled.
__device__ __forceinline__ int swz(int row, int blk) {
    return row * 32 + ((blk ^ ((row >> 1) & 3)) << 3);
}

__global__ __launch_bounds__(256) void cast_bf16(
    const float* __restrict__ in, unsigned short* __restrict__ out, int n)
{
    int i = (blockIdx.x * 256 + threadIdx.x) * 4;
    if (i >= n) return;
    float4 x = *(const float4*)(in + i);
    ushort4 h;
    h.x = f2bf(x.x); h.y = f2bf(x.y); h.z = f2bf(x.z); h.w = f2bf(x.w);
    *(ushort4*)(out + i) = h;
}

__global__ __launch_bounds__(256) void split_bf16(
    const float* __restrict__ in, unsigned short* __restrict__ hi,
    unsigned short* __restrict__ lo, int n)
{
    int i = (blockIdx.x * 256 + threadIdx.x) * 4;
    if (i >= n) return;
    float4 x = *(const float4*)(in + i);
    ushort4 h, l;
    h.x = f2bf(x.x); l.x = f2bf(x.x - bf2f(h.x));
    h.y = f2bf(x.y); l.y = f2bf(x.y - bf2f(h.y));
    h.z = f2bf(x.z); l.z = f2bf(x.z - bf2f(h.z));
    h.w = f2bf(x.w); l.w = f2bf(x.w - bf2f(h.w));
    *(ushort4*)(hi + i) = h;
    *(ushort4*)(lo + i) = l;
}

// Fused QKV: C[m,n] = sum_k x[m,k] * Wqkv[n,k]; n in [0,3072); bf16 out to
// q/k/v per 1024-col range. 128x128 tile, BK=32, 4 waves, 1 MFMA per frag.
#define BK 32
__global__ __launch_bounds__(256) void gemm_qkv(
    const unsigned short* __restrict__ A, const unsigned short* __restrict__ Bw,
    unsigned short* __restrict__ Q, unsigned short* __restrict__ Kp,
    unsigned short* __restrict__ V)
{
    __shared__ unsigned short pool[128 * 132];   // staging (2x4096) then epilogue
    unsigned short* sA = pool;
    unsigned short* sB = pool + 128 * BK;
    const int t = threadIdx.x, lane = t & 63, wave = t >> 6;
    const int m0 = blockIdx.y * 128, n0 = blockIdx.x * 128;
    const int wm = (wave & 1) * 64, wn = (wave >> 1) * 64;
    const int srow = wave * 32 + (lane >> 2);
    const int scol = ((lane & 3) ^ ((lane >> 3) & 3)) * 8;   // swizzled fetch col
    const int fr = lane & 15, g4 = lane >> 4;

    f32x4 acc[4][4];
#pragma unroll
    for (int i = 0; i < 4; ++i)
#pragma unroll
        for (int j = 0; j < 4; ++j) acc[i][j] = (f32x4)0.f;

    for (int k0 = 0; k0 < D_; k0 += BK) {
        __syncthreads();
#pragma unroll
        for (int i = 0; i < 2; ++i) {
            const size_t ga = (size_t)(m0 + srow + i * 16) * D_ + k0 + scol;
            const size_t gb = (size_t)(n0 + srow + i * 16) * D_ + k0 + scol;
            const int lb = (wave * 32 + i * 16) * BK;
            load_lds16(A + ga, &sA[lb]);
            load_lds16(Bw + gb, &sB[lb]);
        }
        __syncthreads();
        short8 a[4], b[4];
#pragma unroll
        for (int i = 0; i < 4; ++i) a[i] = *(const short8*)&sA[swz(wm + i * 16 + fr, g4)];
#pragma unroll
        for (int j = 0; j < 4; ++j) b[j] = *(const short8*)&sB[swz(wn + j * 16 + fr, g4)];
#pragma unroll
        for (int i = 0; i < 4; ++i)
#pragma unroll
            for (int j = 0; j < 4; ++j)
                acc[i][j] = __builtin_amdgcn_mfma_f32_16x16x32_bf16(a[i], b[j], acc[i][j], 0, 0, 0);
    }
    __syncthreads();   // everyone done reading sA/sB
    const int ccol = lane & 15, crow = (lane >> 4) * 4;
#pragma unroll
    for (int i = 0; i < 4; ++i)
#pragma unroll
        for (int j = 0; j < 4; ++j)
#pragma unroll
            for (int r = 0; r < 4; ++r)
                pool[(wm + i * 16 + crow + r) * 132 + wn + j * 16 + ccol] = f2bf(acc[i][j][r]);
    __syncthreads();
    const int which = n0 >> 10, col0 = n0 & 1023;
    unsigned short* outp = which == 0 ? Q : (which == 1 ? Kp : V);
    const int row = t >> 1, ch = (t & 1) * 64;
    unsigned short* gp = outp + (size_t)(m0 + row) * D_ + col0 + ch;
    const unsigned short* lp = &pool[row * 132 + ch];
#pragma unroll
    for (int u = 0; u < 64; u += 8)
        *(ushort8*)(gp + u) = *(const ushort8*)(lp + u);
}

// Out-GEMM: C[m,n] = sum_k A[m,k]*B[n,k], split-bf16 (3 MFMA), fp32 C. Swizzled.
__global__ __launch_bounds__(256) void gemm_bt_split(
    const unsigned short* __restrict__ Ah, const unsigned short* __restrict__ Al,
    const unsigned short* __restrict__ Bh, const unsigned short* __restrict__ Bl,
    float* __restrict__ C, int M, int N, int K)
{
    __shared__ unsigned short sAh[128 * BK], sAl[128 * BK];
    __shared__ unsigned short sBh[128 * BK], sBl[128 * BK];
    const int t = threadIdx.x, lane = t & 63, wave = t >> 6;
    const int m0 = blockIdx.y * 128, n0 = blockIdx.x * 128;
    const int wm = (wave & 1) * 64, wn = (wave >> 1) * 64;
    const int srow = wave * 32 + (lane >> 2);
    const int scol = ((lane & 3) ^ ((lane >> 3) & 3)) * 8;
    const int fr = lane & 15, g4 = lane >> 4;

    f32x4 acc[4][4];
#pragma unroll
    for (int i = 0; i < 4; ++i)
#pragma unroll
        for (int j = 0; j < 4; ++j) acc[i][j] = (f32x4)0.f;

    for (int k0 = 0; k0 < K; k0 += BK) {
        __syncthreads();
#pragma unroll
        for (int i = 0; i < 2; ++i) {
            const size_t ga = (size_t)(m0 + srow + i * 16) * K + k0 + scol;
            const size_t gb = (size_t)(n0 + srow + i * 16) * K + k0 + scol;
            const int lb = (wave * 32 + i * 16) * BK;
            load_lds16(Ah + ga, &sAh[lb]);
            load_lds16(Al + ga, &sAl[lb]);
            load_lds16(Bh + gb, &sBh[lb]);
            load_lds16(Bl + gb, &sBl[lb]);
        }
        __syncthreads();
        short8 ah[4], al[4], bh[4], bl[4];
#pragma unroll
        for (int i = 0; i < 4; ++i) {
            ah[i] = *(const short8*)&sAh[swz(wm + i * 16 + fr, g4)];
            al[i] = *(const short8*)&sAl[swz(wm + i * 16 + fr, g4)];
            bh[i] = *(const short8*)&sBh[swz(wn + i * 16 + fr, g4)];
            bl[i] = *(const short8*)&sBl[swz(wn + i * 16 + fr, g4)];
        }
#pragma unroll
        for (int i = 0; i < 4; ++i)
#pragma unroll
            for (int j = 0; j < 4; ++j) {
                acc[i][j] = __builtin_amdgcn_mfma_f32_16x16x32_bf16(ah[i], bh[j], acc[i][j], 0, 0, 0);
                acc[i][j] = __builtin_amdgcn_mfma_f32_16x16x32_bf16(al[i], bh[j], acc[i][j], 0, 0, 0);
                acc[i][j] = __builtin_amdgcn_mfma_f32_16x16x32_bf16(ah[i], bl[j], acc[i][j], 0, 0, 0);
            }
    }
    const int ccol = lane & 15, crow = (lane >> 4) * 4;
#pragma unroll
    for (int i = 0; i < 4; ++i)
#pragma unroll
        for (int j = 0; j < 4; ++j) {
            float* cp = C + (size_t)(m0 + wm + i * 16 + crow) * N + (n0 + wn + j * 16 + ccol);
#pragma unroll
            for (int r = 0; r < 4; ++r) cp[(size_t)r * N] = acc[i][j][r];
        }
}

// Per (b,h,seg): M_seg[d][v], zsum[d], and V^T bf16 tile. Inputs bf16.
__global__ __launch_bounds__(256) void seg_stats(
    const unsigned short* __restrict__ kproj, const unsigned short* __restrict__ vproj,
    float* __restrict__ Mseg, float* __restrict__ zsum,
    unsigned short* __restrict__ vtg)
{
    __shared__ float ks[64][68];
    __shared__ float vs[64][68];
    const int idx = blockIdx.x;
    const int seg = idx & 15;
    const int bh  = idx >> 4;
    const int h   = bh & 15;
    const int b   = bh >> 4;
    const size_t base = ((size_t)b * T_ + (size_t)seg * SEG_ + (size_t)h * 32) * D_;
    const unsigned short* kt = kproj + base;
    const unsigned short* vt = vproj + base;
    const int t  = threadIdx.x;
    const int d0 = (t >> 4) * 4;
    const int v0 = (t & 15) * 4;
    const int lr = t >> 2;
    const int lc = (t & 3) * 16;
    float acc[4][4];
#pragma unroll
    for (int i = 0; i < 4; ++i)
#pragma unroll
        for (int j = 0; j < 4; ++j) acc[i][j] = 0.f;
    float zacc = 0.f;

    for (int c0 = 0; c0 < SEG_; c0 += 64) {
        __syncthreads();
        {
            const unsigned short* kp = kt + (size_t)(c0 + lr) * 64 + lc;
            const unsigned short* vp = vt + (size_t)(c0 + lr) * 64 + lc;
            ushort8 k0 = *(const ushort8*)kp,       k1 = *(const ushort8*)(kp + 8);
            ushort8 v0v = *(const ushort8*)vp,      v1 = *(const ushort8*)(vp + 8);
#pragma unroll
            for (int e = 0; e < 8; ++e) {
                ks[lr][lc + e]     = elu1(bf2f(k0[e]));
                ks[lr][lc + 8 + e] = elu1(bf2f(k1[e]));
                vs[lr][lc + e]     = bf2f(v0v[e]);
                vs[lr][lc + 8 + e] = bf2f(v1[e]);
            }
        }
        __syncthreads();
#pragma unroll 8
        for (int i = 0; i < 64; ++i) {
            float a0 = ks[i][d0 + 0], a1 = ks[i][d0 + 1];
            float a2 = ks[i][d0 + 2], a3 = ks[i][d0 + 3];
            float b0 = vs[i][v0 + 0], b1 = vs[i][v0 + 1];
            float b2 = vs[i][v0 + 2], b3 = vs[i][v0 + 3];
            acc[0][0] += a0 * b0; acc[0][1] += a0 * b1; acc[0][2] += a0 * b2; acc[0][3] += a0 * b3;
            acc[1][0] += a1 * b0; acc[1][1] += a1 * b1; acc[1][2] += a1 * b2; acc[1][3] += a1 * b3;
            acc[2][0] += a2 * b0; acc[2][1] += a2 * b1; acc[2][2] += a2 * b2; acc[2][3] += a2 * b3;
            acc[3][0] += a3 * b0; acc[3][1] += a3 * b1; acc[3][2] += a3 * b2; acc[3][3] += a3 * b3;
        }
        if (t < 64) {
#pragma unroll 8
            for (int i = 0; i < 64; ++i) zacc += ks[i][t];
        }
        {   // V^T bf16: row = v-dim (lr), cols = time
            ushort8 w0, w1;
#pragma unroll
            for (int i = 0; i < 8; ++i) w0[i] = f2bf(vs[lc + i][lr]);
#pragma unroll
            for (int i = 0; i < 8; ++i) w1[i] = f2bf(vs[lc + 8 + i][lr]);
            unsigned short* vo = vtg + ((size_t)idx * 64 + lr) * 512 + c0 + lc;
            *(ushort8*)vo       = w0;
            *(ushort8*)(vo + 8) = w1;
        }
    }
    float* Mout = Mseg + (size_t)idx * 4096;
#pragma unroll
    for (int i = 0; i < 4; ++i)
        *(float4*)(Mout + (size_t)(d0 + i) * 64 + v0) =
            make_float4(acc[i][0], acc[i][1], acc[i][2], acc[i][3]);
    if (t < 64) zsum[(size_t)idx * 64 + t] = zacc;
}

// Per (b,h): in-place exclusive prefix of M, inclusive prefix of z.
__global__ __launch_bounds__(256) void prefix_scan(
    float* __restrict__ M, float* __restrict__ z)
{
    const int bh = blockIdx.x;
    const int t  = threadIdx.x;
    float run[16];
#pragma unroll
    for (int u = 0; u < 16; ++u) run[u] = 0.f;
    float runz = 0.f;
    for (int seg = 0; seg < NSEG_; ++seg) {
        const size_t o = ((size_t)bh * NSEG_ + seg) * 4096 + (size_t)t * 16;
#pragma unroll
        for (int u = 0; u < 16; u += 4) {
            float4 m = *(const float4*)(M + o + u);
            *(float4*)(M + o + u) = make_float4(run[u], run[u+1], run[u+2], run[u+3]);
            run[u] += m.x; run[u+1] += m.y; run[u+2] += m.z; run[u+3] += m.w;
        }
        if (t < 64) {
            const size_t oz = ((size_t)bh * NSEG_ + seg) * 64 + t;
            runz += z[oz];
            z[oz] = runz;
        }
    }
}

// MFMA flash attention per (b,h,seg,64-row q-chunk). bf16 q/k/v inputs.
__global__ __launch_bounds__(256) void attn_mfma(
    const unsigned short* __restrict__ qproj, const unsigned short* __restrict__ kproj,
    const unsigned short* __restrict__ vtg, const float* __restrict__ memb,
    const float* __restrict__ Zaf, const float* __restrict__ betas,
    unsigned short* __restrict__ ath, unsigned short* __restrict__ atl)
{
    __shared__ unsigned short sm_k[64 * 72];   // k bf16 ; epilogue att_hi
    __shared__ unsigned short sm_v[64 * 72];   // V^T bf16 ; epilogue att_lo
    __shared__ unsigned short sm_p[64 * 72];   // mem^T bf16, then P bf16
    __shared__ float Zsh[64], gsh[64];

    const int idx  = blockIdx.x;
    const int qc   = idx & 7;
    const int rest = idx >> 3;
    const int seg  = rest & 15;
    const int bh   = rest >> 4;
    const int h    = bh & 15;
    const int b    = bh >> 4;
    const size_t base = ((size_t)b * T_ + (size_t)seg * SEG_ + (size_t)h * 32) * D_;

    const int t    = threadIdx.x;
    const int lane = t & 63;
    const int w    = t >> 6;
    const int c16  = lane & 15;
    const int g4   = lane >> 4;
    const int lr   = t >> 2;
    const int lc   = (t & 3) * 16;

    const unsigned short* qt = qproj + base + (size_t)qc * 4096;
    const unsigned short* kt = kproj + base;
    const unsigned short* vt = vtg + (size_t)rest * (64 * 512);
    const float* mb = memb + (size_t)rest * 4096;

    if (t < 64) {
        Zsh[t] = Zaf[(size_t)rest * 64 + t];
        gsh[t] = 1.f / (1.f + __expf(-betas[h * 64 + t]));
    }

    // q fragments (A-layout: m = w*16+c16, k = g4*8 + ks*32 + j), sq, rowsum
    short8 qh[2], sqh[2];
    float rowsum = 0.f;
#pragma unroll
    for (int ks = 0; ks < 2; ++ks) {
        const unsigned short* qp = qt + (size_t)(w * 16 + c16) * 64 + g4 * 8 + ks * 32;
        ushort8 qv = *(const ushort8*)qp;
        short8 qf, sf;
#pragma unroll
        for (int j = 0; j < 8; ++j) {
            float e = elu1(bf2f(qv[j]));
            rowsum += e;
            qf[j] = (short)qv[j];
            sf[j] = (short)f2bf(e);
        }
        qh[ks] = qf; sqh[ks] = sf;
    }
    rowsum += __shfl_xor(rowsum, 16);
    rowsum += __shfl_xor(rowsum, 32);

    // stage mem^T (bf16) into sm_p
    {
        const float* mp = mb + (size_t)lr * 64 + lc;
#pragma unroll
        for (int u = 0; u < 4; ++u) {
            float4 m4 = *(const float4*)(mp + u * 4);
            sm_p[(lc + u * 4 + 0) * 72 + lr] = f2bf(m4.x);
            sm_p[(lc + u * 4 + 1) * 72 + lr] = f2bf(m4.y);
            sm_p[(lc + u * 4 + 2) * 72 + lr] = f2bf(m4.z);
            sm_p[(lc + u * 4 + 3) * 72 + lr] = f2bf(m4.w);
        }
    }
    __syncthreads();

    // num = sq @ mem  (B-operand = mem^T[v][d])
    f32x4 numf[4];
#pragma unroll
    for (int nf = 0; nf < 4; ++nf) numf[nf] = (f32x4)0.f;
#pragma unroll
    for (int ks = 0; ks < 2; ++ks)
#pragma unroll
        for (int nf = 0; nf < 4; ++nf) {
            short8 bm = *(const short8*)&sm_p[(nf * 16 + c16) * 72 + g4 * 8 + ks * 32];
            numf[nf] = __builtin_amdgcn_mfma_f32_16x16x32_bf16(sqh[ks], bm, numf[nf], 0, 0, 0);
        }

    f32x4 o[4];
#pragma unroll
    for (int nf = 0; nf < 4; ++nf) o[nf] = (f32x4)0.f;
    float mrow[4] = {-1e30f, -1e30f, -1e30f, -1e30f};
    float lrow[4] = {0.f, 0.f, 0.f, 0.f};

    for (int kb = 0; kb < 8; ++kb) {
        __syncthreads();
        {   // stage k and V^T (both already bf16 — raw 16B copies)
            const unsigned short* kp = kt + (size_t)(kb * 64 + lr) * 64 + lc;
            *(ushort8*)&sm_k[lr * 72 + lc]     = *(const ushort8*)kp;
            *(ushort8*)&sm_k[lr * 72 + lc + 8] = *(const ushort8*)(kp + 8);
            const unsigned short* vp = vt + (size_t)lr * 512 + kb * 64 + lc;
            *(ushort8*)&sm_v[lr * 72 + lc]     = *(const ushort8*)vp;
            *(ushort8*)&sm_v[lr * 72 + lc + 8] = *(const ushort8*)(vp + 8);
        }
        __syncthreads();

        // scores S = Q @ K^T
        f32x4 s[4];
#pragma unroll
        for (int nf = 0; nf < 4; ++nf) s[nf] = (f32x4)0.f;
#pragma unroll
        for (int ks = 0; ks < 2; ++ks)
#pragma unroll
            for (int nf = 0; nf < 4; ++nf) {
                short8 bk = *(const short8*)&sm_k[(nf * 16 + c16) * 72 + g4 * 8 + ks * 32];
                s[nf] = __builtin_amdgcn_mfma_f32_16x16x32_bf16(qh[ks], bk, s[nf], 0, 0, 0);
            }
#pragma unroll
        for (int nf = 0; nf < 4; ++nf) s[nf] *= 0.125f;

        float corr[4];
#pragma unroll
        for (int r = 0; r < 4; ++r) {
            float mx = fmaxf(fmaxf(s[0][r], s[1][r]), fmaxf(s[2][r], s[3][r]));
            mx = fmaxf(mx, __shfl_xor(mx, 1));
            mx = fmaxf(mx, __shfl_xor(mx, 2));
            mx = fmaxf(mx, __shfl_xor(mx, 4));
            mx = fmaxf(mx, __shfl_xor(mx, 8));
            float mnew = fmaxf(mrow[r], mx);
            corr[r] = __expf(mrow[r] - mnew);
            mrow[r] = mnew;
        }
#pragma unroll
        for (int nf = 0; nf < 4; ++nf)
#pragma unroll
            for (int r = 0; r < 4; ++r)
                s[nf][r] = __expf(s[nf][r] - mrow[r]);
#pragma unroll
        for (int r = 0; r < 4; ++r) {
            float ps = s[0][r] + s[1][r] + s[2][r] + s[3][r];
            ps += __shfl_xor(ps, 1);
            ps += __shfl_xor(ps, 2);
            ps += __shfl_xor(ps, 4);
            ps += __shfl_xor(ps, 8);
            lrow[r] = lrow[r] * corr[r] + ps;
        }
#pragma unroll
        for (int nf = 0; nf < 4; ++nf)
#pragma unroll
            for (int r = 0; r < 4; ++r) o[nf][r] *= corr[r];

        // publish P (C-layout -> A-layout), same-wave rows only: no barrier
#pragma unroll
        for (int nf = 0; nf < 4; ++nf)
#pragma unroll
            for (int r = 0; r < 4; ++r)
                sm_p[(w * 16 + g4 * 4 + r) * 72 + nf * 16 + c16] = f2bf(s[nf][r]);

        // O += P @ V  (B-operand = V^T[v][t])
#pragma unroll
        for (int ks = 0; ks < 2; ++ks) {
            short8 pa = *(const short8*)&sm_p[(w * 16 + c16) * 72 + g4 * 8 + ks * 32];
#pragma unroll
            for (int nf = 0; nf < 4; ++nf) {
                short8 bv = *(const short8*)&sm_v[(nf * 16 + c16) * 72 + g4 * 8 + ks * 32];
                o[nf] = __builtin_amdgcn_mfma_f32_16x16x32_bf16(pa, bv, o[nf], 0, 0, 0);
            }
        }
    }

    __syncthreads();   // staging done — reuse sm_k/sm_v for att hi/lo

    float rs[4], invl[4];
#pragma unroll
    for (int r = 0; r < 4; ++r) {
        rs[r]   = __shfl(rowsum, (g4 << 2) + r);
        invl[r] = 1.f / lrow[r];
    }
#pragma unroll
    for (int nf = 0; nf < 4; ++nf) {
        const int col = nf * 16 + c16;
        const float Zc = Zsh[col], gc = gsh[col];
        const float izc = 1.f / Zc;
#pragma unroll
        for (int r = 0; r < 4; ++r) {
            const float adot = o[nf][r] * invl[r];
            const float amem = numf[nf][r] * izc / rs[r];
            const float res  = gc * amem + (1.f - gc) * adot;
            const unsigned short hv = f2bf(res);
            const unsigned short lv = f2bf(res - bf2f(hv));
            const int row = w * 16 + g4 * 4 + r;
            sm_k[row * 72 + col] = hv;
            sm_v[row * 72 + col] = lv;
        }
    }
    __syncthreads();
    {
        const size_t ob = base + (size_t)(qc * 64 + lr) * 64 + lc;
        *(ushort8*)(ath + ob)     = *(const ushort8*)&sm_k[lr * 72 + lc];
        *(ushort8*)(ath + ob + 8) = *(const ushort8*)&sm_k[lr * 72 + lc + 8];
        *(ushort8*)(atl + ob)     = *(const ushort8*)&sm_v[lr * 72 + lc];
        *(ushort8*)(atl + ob + 8) = *(const ushort8*)&sm_v[lr * 72 + lc + 8];
    }
}

extern "C" void kernel_launch(void* const* d_in, const int* in_sizes, int n_in,
                              void* d_out, int out_size, void* d_ws, size_t ws_size,
                              hipStream_t stream) {
    const float* x     = (const float*)d_in[0];
    const float* Wq    = (const float*)d_in[1];
    const float* Wk    = (const float*)d_in[2];
    const float* Wv    = (const float*)d_in[3];
    const float* Wout  = (const float*)d_in[4];
    const float* betas = (const float*)d_in[5];
    float* out = (float*)d_out;
    (void)d_ws; (void)ws_size;

    float *M, *z;
    unsigned short *qb, *kb, *vb, *xh, *wqkv, *vt, *ath, *atl, *woh, *wol;
    hipGetSymbolAddress((void**)&qb,   HIP_SYMBOL(g_qb));
    hipGetSymbolAddress((void**)&kb,   HIP_SYMBOL(g_kb));
    hipGetSymbolAddress((void**)&vb,   HIP_SYMBOL(g_vb));
    hipGetSymbolAddress((void**)&xh,   HIP_SYMBOL(g_xh));
    hipGetSymbolAddress((void**)&wqkv, HIP_SYMBOL(g_wqkv));
    hipGetSymbolAddress((void**)&vt,   HIP_SYMBOL(g_vt));
    hipGetSymbolAddress((void**)&ath,  HIP_SYMBOL(g_ath));
    hipGetSymbolAddress((void**)&atl,  HIP_SYMBOL(g_atl));
    hipGetSymbolAddress((void**)&woh,  HIP_SYMBOL(g_woh));
    hipGetSymbolAddress((void**)&wol,  HIP_SYMBOL(g_wol));
    hipGetSymbolAddress((void**)&M,    HIP_SYMBOL(g_M));
    hipGetSymbolAddress((void**)&z,    HIP_SYMBOL(g_z));

    const int nX = (int)NPROJ, nW = (int)NW;
    cast_bf16<<<nX / 1024, 256, 0, stream>>>(x, xh, nX);
    cast_bf16<<<nW / 1024, 256, 0, stream>>>(Wq, wqkv, nW);
    cast_bf16<<<nW / 1024, 256, 0, stream>>>(Wk, wqkv + NW, nW);
    cast_bf16<<<nW / 1024, 256, 0, stream>>>(Wv, wqkv + 2 * NW, nW);
    split_bf16<<<nW / 1024, 256, 0, stream>>>(Wout, woh, wol, nW);

    gemm_qkv<<<dim3(3 * D_ / 128, BT_ / 128), 256, 0, stream>>>(xh, wqkv, qb, kb, vb);
    seg_stats<<<B_ * H_ * NSEG_, 256, 0, stream>>>(kb, vb, M, z, vt);
    prefix_scan<<<B_ * H_, 256, 0, stream>>>(M, z);
    attn_mfma<<<B_ * H_ * NSEG_ * 8, 256, 0, stream>>>(qb, kb, vt, M, z, betas, ath, atl);
    gemm_bt_split<<<dim3(D_ / 128, BT_ / 128), 256, 0, stream>>>(ath, atl, woh, wol, out, BT_, D_, D_);
}